// Round 12
// baseline (10894.213 us; speedup 1.0000x reference)
//
#include <hip/hip_runtime.h>
#include <math.h>

// OptNet IPM QP solve via Woodbury, Round 12: 3-wave k_C + strip trailing.
//  M = Q + G^T D G;  M^{-1} = Qi - Qi G^T (Dinv + K)^{-1} G Qi,  K = G Qi G^T
// Base = round 11 (8.09 ms best). k_C: 192 threads (3 waves; LDS 34.5KB x 4
// blocks/CU = 12 waves/CU vs 8) and trailing tiles assigned as contiguous
// strips per thread so the Pi panel block is register-cached across tiles in
// the same tile-row (~33% fewer ds_read_b128). Per-tile arithmetic identical.

#define B_TOT 2560
#define TB 32
#define NB (B_TOT/TB)
#define NTC 192        // k_C threads

__device__ __forceinline__ int ROFF(int i){ return (i*(i+1))>>1; }
// padded-row packed lower triangle: row i starts at rowStart(i), 16B aligned
__device__ __forceinline__ int rowStart(int i){
  int a=i>>2, b=i&3;
  return ((a+1)*((a<<1)+b))<<2;
}
#define TRI_SZ 8448

__device__ __forceinline__ int rowOfIdx(int idx){
  int i = (int)((sqrtf(8.f*(float)idx+1.f)-1.f)*0.5f);
  while (((i+1)*(i+2)>>1) <= idx) ++i;
  while (((i*(i+1))>>1) > idx) --i;
  return i;
}

// ---- Gauss-Jordan 16x16 diag block: factor AND invert (lanes 0..15 of one wave)
// On exit diag slots hold Linv (lower). ----
__device__ __forceinline__ void chol_diag_gj(float* tri, int c0, int lane){
  float rowA[16], rowW[16];
  const int r = lane;
  #pragma unroll
  for (int j=0;j<16;++j){ rowA[j]=0.f; rowW[j]=0.f; }
  if (r < 16){
    const float* src = &tri[rowStart(c0+r)+c0];
    #pragma unroll
    for (int q=0;q<4;++q){
      if (q <= (r>>2)){
        float4 w = *(const float4*)&src[4*q];
        rowA[4*q+0]=w.x; rowA[4*q+1]=w.y; rowA[4*q+2]=w.z; rowA[4*q+3]=w.w;
      }
    }
    #pragma unroll
    for (int j=0;j<16;++j) if (j>r) rowA[j]=0.f;
    #pragma unroll
    for (int j=0;j<16;++j) rowW[j] = (j==r)?1.f:0.f;
  }
  #pragma unroll
  for (int k=0;k<16;++k){
    float akk = __shfl(rowA[k], k, 64);
    akk = fmaxf(akk, 1e-12f);
    float linv = rsqrtf(akk);
    float lrk = rowA[k]*linv;
    if (r==k){
      #pragma unroll
      for (int c=0;c<16;++c) rowW[c] *= linv;
    }
    #pragma unroll
    for (int j=k+1;j<16;++j){
      float ljk = __shfl(lrk, j, 64);
      if (r>=j) rowA[j] = fmaf(-lrk, ljk, rowA[j]);
    }
    #pragma unroll
    for (int c=0;c<=k;++c){
      float wkc = __shfl(rowW[c], k, 64);
      if (r>k) rowW[c] = fmaf(-lrk, wkc, rowW[c]);
    }
  }
  if (r < 16){
    float* dst = &tri[rowStart(c0+r)+c0];
    #pragma unroll
    for (int q=0;q<4;++q){
      if (q <= (r>>2)){
        float4 w; w.x=rowW[4*q+0]; w.y=rowW[4*q+1]; w.z=rowW[4*q+2]; w.w=rowW[4*q+3];
        *(float4*)&dst[4*q] = w;
      }
    }
  }
}

// ---- 8x8 trailing tile (k_prepA only) ----
__device__ __forceinline__ void trail_tile8(float* tri, int pc0, int i0, int j0,
                                            bool diag){
  float4 Pi[8][4], Pj[8][4];
  #pragma unroll
  for (int ii=0;ii<8;++ii){
    const float* rp = &tri[rowStart(i0+ii)+pc0];
    #pragma unroll
    for (int q=0;q<4;++q) Pi[ii][q] = *(const float4*)&rp[4*q];
  }
  #pragma unroll
  for (int jj=0;jj<8;++jj){
    const float* rp = &tri[rowStart(j0+jj)+pc0];
    #pragma unroll
    for (int q=0;q<4;++q) Pj[jj][q] = *(const float4*)&rp[4*q];
  }
  float acc[8][8];
  #pragma unroll
  for (int ii=0;ii<8;++ii)
    #pragma unroll
    for (int jj=0;jj<8;++jj) acc[ii][jj]=0.f;
  #pragma unroll
  for (int q=0;q<4;++q){
    #pragma unroll
    for (int ii=0;ii<8;++ii){
      #pragma unroll
      for (int jj=0;jj<8;++jj){
        acc[ii][jj] = fmaf(Pi[ii][q].x, Pj[jj][q].x, acc[ii][jj]);
        acc[ii][jj] = fmaf(Pi[ii][q].y, Pj[jj][q].y, acc[ii][jj]);
        acc[ii][jj] = fmaf(Pi[ii][q].z, Pj[jj][q].z, acc[ii][jj]);
        acc[ii][jj] = fmaf(Pi[ii][q].w, Pj[jj][q].w, acc[ii][jj]);
      }
    }
  }
  if (!diag){
    #pragma unroll
    for (int ii=0;ii<8;++ii){
      float4* p = (float4*)&tri[rowStart(i0+ii)+j0];
      float4 v0=p[0], v1=p[1];
      v0.x-=acc[ii][0]; v0.y-=acc[ii][1]; v0.z-=acc[ii][2]; v0.w-=acc[ii][3];
      v1.x-=acc[ii][4]; v1.y-=acc[ii][5]; v1.z-=acc[ii][6]; v1.w-=acc[ii][7];
      p[0]=v0; p[1]=v1;
    }
  } else {
    #pragma unroll
    for (int ii=0;ii<8;++ii){
      float4* p = (float4*)&tri[rowStart(i0+ii)+j0];
      const int nq = (ii>>2)+1;
      #pragma unroll
      for (int q=0;q<2;++q){
        if (q<nq){
          float4 v=p[q];
          v.x-=acc[ii][4*q+0]; v.y-=acc[ii][4*q+1];
          v.z-=acc[ii][4*q+2]; v.w-=acc[ii][4*q+3];
          p[q]=v;
        }
      }
    }
  }
}

// ---- 4x4 trailing tile body with preloaded Pi (k_C strip scheme) ----
__device__ __forceinline__ void trail_tile4_pi(float* tri, int pc0,
                                               const float4 Pi[4][4],
                                               int i0, int j0){
  float4 Pj[4][4];
  #pragma unroll
  for (int jj=0;jj<4;++jj){
    const float* rp = &tri[rowStart(j0+jj)+pc0];
    #pragma unroll
    for (int q=0;q<4;++q) Pj[jj][q] = *(const float4*)&rp[4*q];
  }
  float acc[4][4];
  #pragma unroll
  for (int ii=0;ii<4;++ii)
    #pragma unroll
    for (int jj=0;jj<4;++jj) acc[ii][jj]=0.f;
  #pragma unroll
  for (int q=0;q<4;++q){
    #pragma unroll
    for (int ii=0;ii<4;++ii){
      #pragma unroll
      for (int jj=0;jj<4;++jj){
        acc[ii][jj] = fmaf(Pi[ii][q].x, Pj[jj][q].x, acc[ii][jj]);
        acc[ii][jj] = fmaf(Pi[ii][q].y, Pj[jj][q].y, acc[ii][jj]);
        acc[ii][jj] = fmaf(Pi[ii][q].z, Pj[jj][q].z, acc[ii][jj]);
        acc[ii][jj] = fmaf(Pi[ii][q].w, Pj[jj][q].w, acc[ii][jj]);
      }
    }
  }
  #pragma unroll
  for (int ii=0;ii<4;++ii){
    float4* p = (float4*)&tri[rowStart(i0+ii)+j0];
    float4 v=p[0];
    v.x-=acc[ii][0]; v.y-=acc[ii][1]; v.z-=acc[ii][2]; v.w-=acc[ii][3];
    p[0]=v;
  }
}

__device__ __forceinline__ void load_pi4(const float* tri, int pc0, int i0,
                                         float4 Pi[4][4]){
  #pragma unroll
  for (int ii=0;ii<4;++ii){
    const float* rp = &tri[rowStart(i0+ii)+pc0];
    #pragma unroll
    for (int q=0;q<4;++q) Pi[ii][q] = *(const float4*)&rp[4*q];
  }
}

// ---- panel solve row: X = A * Linv^T (one row) ----
__device__ __forceinline__ void panel_row(float* tri, int c0, int r){
  const int rb = rowStart(r)+c0;
  float a[16];
  #pragma unroll
  for (int q=0;q<4;++q){
    float4 w = *(const float4*)&tri[rb+4*q];
    a[4*q+0]=w.x; a[4*q+1]=w.y; a[4*q+2]=w.z; a[4*q+3]=w.w;
  }
  float x[16];
  #pragma unroll
  for (int c=0;c<16;++c){
    float acc=0.f;
    const int lb = rowStart(c0+c)+c0;
    #pragma unroll
    for (int q=0;q<=(c>>2);++q){
      float4 w = *(const float4*)&tri[lb+4*q];
      if (4*q+0<=c) acc = fmaf(w.x, a[4*q+0], acc);
      if (4*q+1<=c) acc = fmaf(w.y, a[4*q+1], acc);
      if (4*q+2<=c) acc = fmaf(w.z, a[4*q+2], acc);
      if (4*q+3<=c) acc = fmaf(w.w, a[4*q+3], acc);
    }
    x[c]=acc;
  }
  #pragma unroll
  for (int q=0;q<4;++q){
    float4 w; w.x=x[4*q+0]; w.y=x[4*q+1]; w.z=x[4*q+2]; w.w=x[4*q+3];
    *(float4*)&tri[rb+4*q] = w;
  }
}

// ---- 256-thread blocked Cholesky (k_prepA only) ----
__device__ void chol_factor(float* tri, int t, int lane, int wid){
  for (int kb=0; kb<8; ++kb){
    const int c0 = kb*16;
    if (wid==(kb&3)) chol_diag_gj(tri, c0, lane);
    __syncthreads();
    const int rem = 112 - c0;
    if (t < rem) panel_row(tri, c0, c0+16+t);
    __syncthreads();
    if (rem > 0){
      const int base = c0+16;
      const int T = rem>>3;
      const int ntile = (T*(T+1))>>1;
      for (int idx=t; idx<ntile; idx+=256){
        int I = rowOfIdx(idx);
        int J = idx - ROFF(I);
        trail_tile8(tri, c0, base+8*I, base+8*J, I==J);
      }
    }
    __syncthreads();
  }
}

// ---- NTC-thread blocked Cholesky (k_C): strip trailing, Pi cached ----
__device__ void chol_factor_w3(float* tri, int t, int lane, int wid){
  for (int kb=0; kb<8; ++kb){
    const int c0 = kb*16;
    if (wid==0) chol_diag_gj(tri, c0, lane);
    __syncthreads();
    const int rem = 112 - c0;
    if (t < rem) panel_row(tri, c0, c0+16+t);
    __syncthreads();
    if (rem > 0){
      const int base = c0+16;
      const int T = rem>>2;
      const int ntile = (T*(T+1))>>1;
      const int lo = (ntile*t)/NTC;
      const int hi = (ntile*(t+1))/NTC;
      if (lo < hi){
        int I = rowOfIdx(lo);
        int nextRow = ROFF(I+1);
        float4 Pi[4][4];
        load_pi4(tri, c0, base+4*I, Pi);
        for (int idx=lo; idx<hi; ++idx){
          if (idx >= nextRow){
            ++I;
            while (idx >= ROFF(I+1)) ++I;
            nextRow = ROFF(I+1);
            load_pi4(tri, c0, base+4*I, Pi);
          }
          const int J = idx - ROFF(I);
          trail_tile4_pi(tri, c0, Pi, base+4*I, base+4*J);
        }
      }
    }
    __syncthreads();
  }
}

// forward/backward solve; diag slots hold Linv; rhs in LDS (threads >=128 idle)
__device__ void tri_solve_w2(const float* tri, float* rhs, int t){
  for (int kb=0;kb<8;++kb){
    const int c0=kb*16;
    if (t<16){
      const int c=t;
      const float* lrow = &tri[rowStart(c0+c)+c0];
      float acc=0.f;
      #pragma unroll
      for (int cp=0;cp<16;++cp) if (cp<=c) acc = fmaf(lrow[cp], rhs[c0+cp], acc);
      rhs[c0+c] = acc;
    }
    __syncthreads();
    const int rem = 112-c0;
    if (t<rem){
      const int r = c0+16+t;
      const int rb = rowStart(r)+c0;
      float acc = rhs[r];
      #pragma unroll
      for (int q=0;q<4;++q){
        float4 w = *(const float4*)&tri[rb+4*q];
        acc = fmaf(-w.x, rhs[c0+4*q+0], acc);
        acc = fmaf(-w.y, rhs[c0+4*q+1], acc);
        acc = fmaf(-w.z, rhs[c0+4*q+2], acc);
        acc = fmaf(-w.w, rhs[c0+4*q+3], acc);
      }
      rhs[r] = acc;
    }
    __syncthreads();
  }
  for (int kb=7;kb>=0;--kb){
    const int c0=kb*16;
    if (t<16){
      const int c=t;
      float acc=0.f;
      #pragma unroll
      for (int cp=0;cp<16;++cp)
        if (cp>=c) acc = fmaf(tri[rowStart(c0+cp)+c0+c], rhs[c0+cp], acc);
      rhs[c0+c] = acc;
    }
    __syncthreads();
    if (t<c0){
      float acc = rhs[t];
      #pragma unroll
      for (int c=0;c<16;++c) acc = fmaf(-tri[rowStart(c0+c)+t], rhs[c0+c], acc);
      rhs[t]=acc;
    }
    __syncthreads();
  }
}

// ---- k_prepA: factor chol(Q), dump triangle to global ----
__global__ __launch_bounds__(256) void k_prepA(const float* __restrict__ Q,
                                               float* __restrict__ TRIQ){
  __shared__ __align__(16) float tri[TRI_SZ];
  const int t = threadIdx.x;
  const int lane = t&63, wid = t>>6;
  for (int idx=t; idx<8256; idx+=256){
    int i = rowOfIdx(idx); int j = idx - ROFF(i);
    tri[rowStart(i)+j] = Q[i*128+j];
  }
  __syncthreads();
  chol_factor(tri, t, lane, wid);
  for (int idx=t; idx<TRI_SZ; idx+=256) TRIQ[idx]=tri[idx];
}

// ---- k_prepB: 8 blocks, each one 32-col solve chunk -> Qi or M1 ----
__global__ __launch_bounds__(256) void k_prepB(const float* __restrict__ TRIQ,
        const float* __restrict__ Gm, float* __restrict__ Qi, float* __restrict__ M1)
{
  __shared__ __align__(16) float tri[TRI_SZ];
  __shared__ float Xl[128*32];
  const int t = threadIdx.x, cc = blockIdx.x;
  const int a0 = (cc&3)*32;
  const bool ident = (cc<4);
  for (int idx=t; idx<TRI_SZ; idx+=256) tri[idx]=TRIQ[idx];
  for (int idx=t; idx<4096; idx+=256){
    int i=idx>>5, j=idx&31;
    Xl[idx] = ident ? ((i==(a0+j))?1.f:0.f) : Gm[(a0+j)*128+i];
  }
  __syncthreads();
  for (int kb=0;kb<8;++kb){                    // forward: X := L^{-1} X
    const int c0=kb*16;
    if (t<32){
      float v[16], x[16];
      #pragma unroll
      for (int c=0;c<16;++c) v[c]=Xl[(c0+c)*32+t];
      #pragma unroll
      for (int c=0;c<16;++c){
        float acc=0.f;
        const int lb=rowStart(c0+c)+c0;
        #pragma unroll
        for (int cp=0;cp<16;++cp) if (cp<=c) acc=fmaf(tri[lb+cp], v[cp], acc);
        x[c]=acc;
      }
      #pragma unroll
      for (int c=0;c<16;++c) Xl[(c0+c)*32+t]=x[c];
    }
    __syncthreads();
    const int rem=112-c0;
    for (int rr=(t>>5); rr<rem; rr+=8){
      const int r=c0+16+rr, j=t&31;
      float acc=Xl[r*32+j];
      #pragma unroll
      for (int c=0;c<16;++c) acc = fmaf(-tri[rowStart(r)+c0+c], Xl[(c0+c)*32+j], acc);
      Xl[r*32+j]=acc;
    }
    __syncthreads();
  }
  for (int kb=7;kb>=0;--kb){                   // backward: X := L^{-T} X
    const int c0=kb*16;
    if (t<32){
      float v[16], x[16];
      #pragma unroll
      for (int c=0;c<16;++c) v[c]=Xl[(c0+c)*32+t];
      #pragma unroll
      for (int c=0;c<16;++c){
        float acc=0.f;
        #pragma unroll
        for (int cp=0;cp<16;++cp) if (cp>=c) acc=fmaf(tri[rowStart(c0+cp)+c0+c], v[cp], acc);
        x[c]=acc;
      }
      #pragma unroll
      for (int c=0;c<16;++c) Xl[(c0+c)*32+t]=x[c];
    }
    __syncthreads();
    for (int rr=(t>>5); rr<c0; rr+=8){
      const int j=t&31;
      float acc=Xl[rr*32+j];
      #pragma unroll
      for (int c=0;c<16;++c) acc = fmaf(-tri[rowStart(c0+c)+rr], Xl[(c0+c)*32+j], acc);
      Xl[rr*32+j]=acc;
    }
    __syncthreads();
  }
  float* dst = ident ? Qi : M1;
  for (int idx=t; idx<4096; idx+=256){
    int i=idx>>5, j=idx&31;
    dst[i*128+a0+j] = Xl[idx];
  }
}

__global__ __launch_bounds__(256) void k_kmat(const float* __restrict__ Gm,
        const float* __restrict__ M1, float* __restrict__ K, float* __restrict__ Kd){
  const int idx = blockIdx.x*256 + threadIdx.x;
  const int a = idx>>7, bcol = idx&127;
  float a0=0.f,a1=0.f,a2=0.f,a3=0.f;
  #pragma unroll
  for (int j=0;j<128;j+=4){
    a0 = fmaf(Gm[a*128+j+0], M1[(j+0)*128+bcol], a0);
    a1 = fmaf(Gm[a*128+j+1], M1[(j+1)*128+bcol], a1);
    a2 = fmaf(Gm[a*128+j+2], M1[(j+2)*128+bcol], a2);
    a3 = fmaf(Gm[a*128+j+3], M1[(j+3)*128+bcol], a3);
  }
  float acc = (a0+a1)+(a2+a3);
  K[idx] = acc;
  if (a==bcol) Kd[a]=acc;
}

__global__ __launch_bounds__(256) void k_init(const float* __restrict__ p,
    float* __restrict__ Pt, float* __restrict__ S, float* __restrict__ LAM,
    float* __restrict__ GZ, float* __restrict__ QZ, float* __restrict__ Zst){
  int idx = blockIdx.x*256 + threadIdx.x;
  if (idx < 128*B_TOT){
    int i = idx/B_TOT, b = idx - i*B_TOT;
    Pt[idx] = p[b*128+i];
    S[idx]=1.f; LAM[idx]=1.f; GZ[idx]=0.f; QZ[idx]=0.f; Zst[idx]=0.f;
  }
}

// ---- k_B: prologue only: stage1 + rhs + tv ----
__global__ __launch_bounds__(256) void k_B(const float* __restrict__ G,
    const float* __restrict__ M1, const float* __restrict__ Pt,
    const float* __restrict__ h,
    const float* __restrict__ S, const float* __restrict__ LAM,
    const float* __restrict__ GZ, const float* __restrict__ QZ,
    float* __restrict__ RHS, float* __restrict__ TV){
  __shared__ float wm_l[128*33];
  __shared__ float rhs_l[128*33];
  __shared__ float part_l[8*33];
  __shared__ float mu_l[TB];
  __shared__ float h_l[128];
  const int t=threadIdx.x, g=t>>5, bl=t&31;
  const int b = blockIdx.x*TB + bl;
  if (t<128) h_l[t]=h[t];
  __syncthreads();
  float sv[16], lv[16], rpv[16];
  float prod=0.f;
  #pragma unroll
  for (int q=0;q<16;++q){
    int i = g + 8*q;
    float s = S[i*B_TOT+b], l = LAM[i*B_TOT+b], gz = GZ[i*B_TOT+b];
    sv[q]=s; lv[q]=l; rpv[q]=gz+s-h_l[i];
    prod += s*l;
  }
  part_l[g*33+bl] = prod;
  __syncthreads();
  if (g==0){
    float m=0.f;
    #pragma unroll
    for (int q=0;q<8;++q) m += part_l[q*33+bl];
    mu_l[bl] = m*(1.f/128.f);
  }
  __syncthreads();
  const float mu = mu_l[bl];
  #pragma unroll
  for (int q=0;q<16;++q){
    int i=g+8*q;
    float rc = sv[q]*lv[q] - 0.1f*mu;
    wm_l[i*33+bl] = (rc - lv[q]*rpv[q])/sv[q] - lv[q];
  }
  __syncthreads();
  const int r0 = g*16;
  float acc[16];
  #pragma unroll
  for (int q=0;q<16;++q) acc[q] = -(QZ[(r0+q)*B_TOT+b] + Pt[(r0+q)*B_TOT+b]);
  #pragma unroll 2
  for (int j=0;j<128;++j){
    float wmv = wm_l[j*33+bl];
    const float4* gp = (const float4*)&G[j*128+r0];
    #pragma unroll
    for (int q4=0;q4<4;++q4){
      float4 gv = gp[q4];
      acc[4*q4+0]=fmaf(gv.x,wmv,acc[4*q4+0]);
      acc[4*q4+1]=fmaf(gv.y,wmv,acc[4*q4+1]);
      acc[4*q4+2]=fmaf(gv.z,wmv,acc[4*q4+2]);
      acc[4*q4+3]=fmaf(gv.w,wmv,acc[4*q4+3]);
    }
  }
  #pragma unroll
  for (int q=0;q<16;++q){
    rhs_l[(r0+q)*33+bl]=acc[q];
    RHS[(r0+q)*B_TOT+b]=acc[q];
  }
  __syncthreads();
  #pragma unroll
  for (int q=0;q<16;++q) acc[q]=0.f;
  #pragma unroll 2
  for (int j=0;j<128;++j){
    float rv = rhs_l[j*33+bl];
    const float4* mp = (const float4*)&M1[j*128+r0];
    #pragma unroll
    for (int q4=0;q4<4;++q4){
      float4 mv = mp[q4];
      acc[4*q4+0]=fmaf(mv.x,rv,acc[4*q4+0]);
      acc[4*q4+1]=fmaf(mv.y,rv,acc[4*q4+1]);
      acc[4*q4+2]=fmaf(mv.z,rv,acc[4*q4+2]);
      acc[4*q4+3]=fmaf(mv.w,rv,acc[4*q4+3]);
    }
  }
  #pragma unroll
  for (int q=0;q<16;++q) TV[(r0+q)*B_TOT+b]=acc[q];
}

// ---- k_C: NTC threads per batch (3 waves) ----
__global__ __launch_bounds__(NTC) void k_C(const float* __restrict__ K,
    const float* __restrict__ Kd, const float* __restrict__ h,
    const float* __restrict__ TV,
    float* __restrict__ S, float* __restrict__ LAM, float* __restrict__ GZ,
    float* __restrict__ Y, float* __restrict__ ALPHA){
  __shared__ __align__(16) float tri[TRI_SZ];
  __shared__ float scl_l[128];
  __shared__ float sh_t[128];
  __shared__ float red[3];
  const int t = threadIdx.x, b = blockIdx.x;
  const int lane = t&63, wid = t>>6;
  float s_t=0.f,l_t=0.f,g_t=0.f,rp_t=0.f;
  float prod = 0.f;
  if (t<128){
    s_t=S[t*B_TOT+b]; l_t=LAM[t*B_TOT+b]; g_t=GZ[t*B_TOT+b];
    rp_t = g_t + s_t - h[t];
    prod = s_t*l_t;
  }
  #pragma unroll
  for (int o=32;o>0;o>>=1) prod += __shfl_xor(prod,o,64);
  if (lane==0) red[wid]=prod;
  __syncthreads();
  const float mu = (red[0]+red[1]+red[2])*(1.f/128.f);
  float rc_t=0.f, di_t=0.f, sc_t=0.f;
  if (t<128){
    rc_t = s_t*l_t - 0.1f*mu;
    di_t = fminf(s_t/l_t, 1e30f);
    sc_t = rsqrtf(Kd[t]+di_t);
    scl_l[t]=sc_t;
    sh_t[t]=TV[t*B_TOT+b]*sc_t;
  }
  __syncthreads();
  // build equilibrated triangle (unit diag): row sweep, coalesced K reads
  #pragma unroll 4
  for (int i=0;i<128;++i){
    if (t<=i) tri[rowStart(i)+t] = (t==i)?1.f : K[i*128+t]*scl_l[i]*sc_t;
  }
  __syncthreads();
  chol_factor_w3(tri, t, lane, wid);
  tri_solve_w2(tri, sh_t, t);
  float y=0.f, gd=0.f, ds=0.f, dl=0.f;
  float ra = 1e9f;
  if (t<128){
    y = sh_t[t]*sc_t;
    gd = di_t*y;                         // G dz = Dinv .* y (Woodbury identity)
    ds = -rp_t - gd;
    dl = (-rc_t - l_t*ds)/s_t;
    if (ds<0.f) ra = -s_t/ds;
    if (dl<0.f) ra = fminf(ra,-l_t/dl);
  }
  #pragma unroll
  for (int o=32;o>0;o>>=1) ra = fminf(ra,__shfl_xor(ra,o,64));
  __syncthreads();
  if (lane==0) red[wid]=ra;
  __syncthreads();
  const float alpha = fminf(1.0f, 0.99f*fminf(fminf(red[0],red[1]),red[2]));
  if (t<128){
    S[t*B_TOT+b]   = s_t + alpha*ds;
    LAM[t*B_TOT+b] = l_t + alpha*dl;
    GZ[t*B_TOT+b]  = g_t + alpha*gd;
    Y[t*B_TOT+b]   = y;
  }
  if (t==0) ALPHA[b]=alpha;
}

// ---- k_DB: fused k_D(iter i) + k_B(iter i+1) ----
__global__ __launch_bounds__(256) void k_DB(const float* __restrict__ G,
    const float* __restrict__ Qi, const float* __restrict__ M1,
    const float* __restrict__ Pt, const float* __restrict__ h,
    const float* __restrict__ S, const float* __restrict__ LAM,
    const float* __restrict__ GZ,
    const float* __restrict__ Y, const float* __restrict__ ALPHA,
    float* __restrict__ Zst, float* __restrict__ QZ,
    float* __restrict__ RHS, float* __restrict__ TV){
  __shared__ float bufA[128*33];   // y -> qz_new -> rhs_new
  __shared__ float bufB[128*33];   // v -> wm
  __shared__ float part_l[8*33];
  __shared__ float mu_l[TB];
  __shared__ float h_l[128];
  const int t=threadIdx.x, g=t>>5, bl=t&31;
  const int b = blockIdx.x*TB + bl;
  const int r0 = g*16;
  if (t<128) h_l[t]=h[t];
  #pragma unroll
  for (int q=0;q<16;++q){
    int i=g+8*q;
    bufA[i*33+bl] = Y[i*B_TOT+b];
  }
  const float alpha = ALPHA[b];
  __syncthreads();
  // ---- part 1: v = RHS - G^T y ----
  float acc[16];
  #pragma unroll
  for (int q=0;q<16;++q) acc[q]=RHS[(r0+q)*B_TOT+b];
  #pragma unroll 2
  for (int j=0;j<128;++j){
    float yv = bufA[j*33+bl];
    const float4* gp=(const float4*)&G[j*128+r0];
    #pragma unroll
    for (int q4=0;q4<4;++q4){
      float4 gv=gp[q4];
      acc[4*q4+0]=fmaf(-gv.x,yv,acc[4*q4+0]);
      acc[4*q4+1]=fmaf(-gv.y,yv,acc[4*q4+1]);
      acc[4*q4+2]=fmaf(-gv.z,yv,acc[4*q4+2]);
      acc[4*q4+3]=fmaf(-gv.w,yv,acc[4*q4+3]);
    }
  }
  __syncthreads();   // all reads of bufA(y) done
  #pragma unroll
  for (int q=0;q<16;++q){
    const int i=r0+q;
    float qz_new = QZ[i*B_TOT+b] + alpha*acc[q];   // qz += a*v (Q dz == v)
    QZ[i*B_TOT+b] = qz_new;
    bufB[i*33+bl] = acc[q];                        // v
    bufA[i*33+bl] = qz_new;
  }
  __syncthreads();
  // ---- dz = Qi v ; z += a dz ----
  #pragma unroll
  for (int q=0;q<16;++q) acc[q]=0.f;
  #pragma unroll 2
  for (int j=0;j<128;++j){
    float vv = bufB[j*33+bl];
    const float4* qp4=(const float4*)&Qi[j*128+r0];
    #pragma unroll
    for (int q4=0;q4<4;++q4){
      float4 qv=qp4[q4];
      acc[4*q4+0]=fmaf(qv.x,vv,acc[4*q4+0]);
      acc[4*q4+1]=fmaf(qv.y,vv,acc[4*q4+1]);
      acc[4*q4+2]=fmaf(qv.z,vv,acc[4*q4+2]);
      acc[4*q4+3]=fmaf(qv.w,vv,acc[4*q4+3]);
    }
  }
  #pragma unroll
  for (int q=0;q<16;++q){
    float* zp=&Zst[(r0+q)*B_TOT+b];
    *zp = *zp + alpha*acc[q];
  }
  __syncthreads();   // all reads of bufB(v) done
  // ---- part 2: k_B stage1 (post-k_C state) ----
  float sv[16], lv[16], rpv[16];
  float prod=0.f;
  #pragma unroll
  for (int q=0;q<16;++q){
    int i = g + 8*q;
    float s = S[i*B_TOT+b], l = LAM[i*B_TOT+b], gz = GZ[i*B_TOT+b];
    sv[q]=s; lv[q]=l; rpv[q]=gz+s-h_l[i];
    prod += s*l;
  }
  part_l[g*33+bl] = prod;
  __syncthreads();
  if (g==0){
    float m=0.f;
    #pragma unroll
    for (int q=0;q<8;++q) m += part_l[q*33+bl];
    mu_l[bl] = m*(1.f/128.f);
  }
  __syncthreads();
  const float mu = mu_l[bl];
  #pragma unroll
  for (int q=0;q<16;++q){
    int i=g+8*q;
    float rc = sv[q]*lv[q] - 0.1f*mu;
    bufB[i*33+bl] = (rc - lv[q]*rpv[q])/sv[q] - lv[q];   // wm
  }
  __syncthreads();
  // ---- rhs = -(qz_new + p) + G^T wm ----
  #pragma unroll
  for (int q=0;q<16;++q) acc[q] = -(bufA[(r0+q)*33+bl] + Pt[(r0+q)*B_TOT+b]);
  #pragma unroll 2
  for (int j=0;j<128;++j){
    float wmv = bufB[j*33+bl];
    const float4* gp = (const float4*)&G[j*128+r0];
    #pragma unroll
    for (int q4=0;q4<4;++q4){
      float4 gv = gp[q4];
      acc[4*q4+0]=fmaf(gv.x,wmv,acc[4*q4+0]);
      acc[4*q4+1]=fmaf(gv.y,wmv,acc[4*q4+1]);
      acc[4*q4+2]=fmaf(gv.z,wmv,acc[4*q4+2]);
      acc[4*q4+3]=fmaf(gv.w,wmv,acc[4*q4+3]);
    }
  }
  __syncthreads();   // wm reads done
  #pragma unroll
  for (int q=0;q<16;++q){
    RHS[(r0+q)*B_TOT+b]=acc[q];
    bufA[(r0+q)*33+bl]=acc[q];
  }
  __syncthreads();
  // ---- tv = G Qi rhs (via M1^T) ----
  #pragma unroll
  for (int q=0;q<16;++q) acc[q]=0.f;
  #pragma unroll 2
  for (int j=0;j<128;++j){
    float rv = bufA[j*33+bl];
    const float4* mp = (const float4*)&M1[j*128+r0];
    #pragma unroll
    for (int q4=0;q4<4;++q4){
      float4 mv = mp[q4];
      acc[4*q4+0]=fmaf(mv.x,rv,acc[4*q4+0]);
      acc[4*q4+1]=fmaf(mv.y,rv,acc[4*q4+1]);
      acc[4*q4+2]=fmaf(mv.z,rv,acc[4*q4+2]);
      acc[4*q4+3]=fmaf(mv.w,rv,acc[4*q4+3]);
    }
  }
  #pragma unroll
  for (int q=0;q<16;++q) TV[(r0+q)*B_TOT+b]=acc[q];
}

// ---- k_D: final iteration tail (v, dz, z, qz) ----
__global__ __launch_bounds__(256) void k_D(const float* __restrict__ G,
    const float* __restrict__ Qi, const float* __restrict__ RHS,
    const float* __restrict__ Y, const float* __restrict__ ALPHA,
    float* __restrict__ Zst, float* __restrict__ QZ){
  __shared__ float y_l[128*33];
  __shared__ float v_l[128*33];
  const int t=threadIdx.x, g=t>>5, bl=t&31;
  const int b = blockIdx.x*TB + bl;
  #pragma unroll
  for (int q=0;q<16;++q){
    int i=g+8*q;
    y_l[i*33+bl] = Y[i*B_TOT+b];
  }
  const float alpha = ALPHA[b];
  __syncthreads();
  const int r0=g*16;
  float acc[16];
  #pragma unroll
  for (int q=0;q<16;++q) acc[q]=RHS[(r0+q)*B_TOT+b];
  #pragma unroll 2
  for (int j=0;j<128;++j){
    float yv = y_l[j*33+bl];
    const float4* gp=(const float4*)&G[j*128+r0];
    #pragma unroll
    for (int q4=0;q4<4;++q4){
      float4 gv=gp[q4];
      acc[4*q4+0]=fmaf(-gv.x,yv,acc[4*q4+0]);
      acc[4*q4+1]=fmaf(-gv.y,yv,acc[4*q4+1]);
      acc[4*q4+2]=fmaf(-gv.z,yv,acc[4*q4+2]);
      acc[4*q4+3]=fmaf(-gv.w,yv,acc[4*q4+3]);
    }
  }
  #pragma unroll
  for (int q=0;q<16;++q){
    v_l[(r0+q)*33+bl]=acc[q];
    float* qp=&QZ[(r0+q)*B_TOT+b];
    *qp = *qp + alpha*acc[q];
  }
  __syncthreads();
  #pragma unroll
  for (int q=0;q<16;++q) acc[q]=0.f;
  #pragma unroll 2
  for (int j=0;j<128;++j){
    float vv = v_l[j*33+bl];
    const float4* qp4=(const float4*)&Qi[j*128+r0];
    #pragma unroll
    for (int q4=0;q4<4;++q4){
      float4 qv=qp4[q4];
      acc[4*q4+0]=fmaf(qv.x,vv,acc[4*q4+0]);
      acc[4*q4+1]=fmaf(qv.y,vv,acc[4*q4+1]);
      acc[4*q4+2]=fmaf(qv.z,vv,acc[4*q4+2]);
      acc[4*q4+3]=fmaf(qv.w,vv,acc[4*q4+3]);
    }
  }
  #pragma unroll
  for (int q=0;q<16;++q){
    float* zp=&Zst[(r0+q)*B_TOT+b];
    *zp = *zp + alpha*acc[q];
  }
}

// out = log_softmax(Z.reshape(10, 32768), axis=1), Z stored n-major [i][B]
__global__ __launch_bounds__(1024) void k_logsoftmax(const float* __restrict__ Zst,
                                                     float* __restrict__ out){
  __shared__ float red[16];
  __shared__ float sval[2];
  const int r = blockIdx.x, t = threadIdx.x;
  float m = -1e30f;
  for (int k=t;k<32768;k+=1024){
    float v = Zst[(k&127)*B_TOT + r*256 + (k>>7)];
    m = fmaxf(m, v);
  }
  #pragma unroll
  for (int o=32;o>0;o>>=1) m = fmaxf(m, __shfl_down(m,o,64));
  if ((t&63)==0) red[t>>6] = m;
  __syncthreads();
  if (t==0){ float mm=red[0]; for (int w=1;w<16;++w) mm=fmaxf(mm,red[w]); sval[0]=mm; }
  __syncthreads();
  const float mx = sval[0];
  float s=0.f;
  for (int k=t;k<32768;k+=1024){
    float v = Zst[(k&127)*B_TOT + r*256 + (k>>7)];
    s += expf(v-mx);
  }
  #pragma unroll
  for (int o=32;o>0;o>>=1) s += __shfl_down(s,o,64);
  if ((t&63)==0) red[t>>6]=s;
  __syncthreads();
  if (t==0){ float ss=0.f; for (int w=0;w<16;++w) ss+=red[w]; sval[1]=logf(ss); }
  __syncthreads();
  const float lse = sval[1];
  for (int k=t;k<32768;k+=1024){
    float v = Zst[(k&127)*B_TOT + r*256 + (k>>7)];
    out[(size_t)r*32768+k] = v-mx-lse;
  }
}

extern "C" void kernel_launch(void* const* d_in, const int* in_sizes, int n_in,
                              void* d_out, int out_size, void* d_ws, size_t ws_size,
                              hipStream_t stream){
  // inputs: 0=x (unused), 1=Q[128x128], 2=p[2560x128], 3=G[128x128], 4=h[128], 5=m
  const float* Q = (const float*)d_in[1];
  const float* p = (const float*)d_in[2];
  const float* G = (const float*)d_in[3];
  const float* h = (const float*)d_in[4];
  float* ws  = (float*)d_ws;
  const int NE = 128*B_TOT;
  float* Zst = ws;                       // NE
  float* Qi  = Zst + NE;                 // 16384
  float* M1  = Qi + 16384;
  float* K   = M1 + 16384;
  float* Kd  = K + 16384;                // 128
  float* ALPHA = Kd + 128;               // 2560
  float* Pt  = ALPHA + 2560;             // NE
  float* S   = Pt + NE;
  float* LAM = S + NE;
  float* GZ  = LAM + NE;
  float* QZ  = GZ + NE;
  float* RHS = QZ + NE;
  float* TV  = RHS + NE;
  float* Y   = TV + NE;
  float* TRIQ= Y + NE;                   // 8448
  float* out = (float*)d_out;

  hipLaunchKernelGGL(k_prepA, dim3(1), dim3(256), 0, stream, Q, TRIQ);
  hipLaunchKernelGGL(k_prepB, dim3(8), dim3(256), 0, stream, TRIQ, G, Qi, M1);
  hipLaunchKernelGGL(k_kmat, dim3(64), dim3(256), 0, stream, G, M1, K, Kd);
  hipLaunchKernelGGL(k_init, dim3((NE+255)/256), dim3(256), 0, stream,
                     p, Pt, S, LAM, GZ, QZ, Zst);
  hipLaunchKernelGGL(k_B, dim3(NB), dim3(256), 0, stream,
                     G, M1, Pt, h, S, LAM, GZ, QZ, RHS, TV);
  for (int it=0; it<20; ++it){
    hipLaunchKernelGGL(k_C, dim3(B_TOT), dim3(NTC), 0, stream,
                       K, Kd, h, TV, S, LAM, GZ, Y, ALPHA);
    if (it < 19){
      hipLaunchKernelGGL(k_DB, dim3(NB), dim3(256), 0, stream,
                         G, Qi, M1, Pt, h, S, LAM, GZ, Y, ALPHA,
                         Zst, QZ, RHS, TV);
    } else {
      hipLaunchKernelGGL(k_D, dim3(NB), dim3(256), 0, stream,
                         G, Qi, RHS, Y, ALPHA, Zst, QZ);
    }
  }
  hipLaunchKernelGGL(k_logsoftmax, dim3(10), dim3(1024), 0, stream, Zst, out);
}

// Round 13
// 7337.657 us; speedup vs baseline: 1.4847x; 1.4847x over previous
//
#include <hip/hip_runtime.h>
#include <math.h>

// OptNet IPM QP solve via Woodbury, Round 13: r11 k_C + wide-grid k_DB.
//  M = Q + G^T D G;  M^{-1} = Qi - Qi G^T (Dinv + K)^{-1} G Qi,  K = G Qi G^T
// k_C = round-11 verbatim (128 thr, wave0 GJ, one-pass panel, round-robin 4x4
// trailing — proven 330us local optimum; 6 perturbations all regressed).
// k_DB rewritten with TB=8 batches/block -> 320 blocks (was 80): 4x wave
// parallelism for the latency-bound GEMV chain. Same per-output accumulation
// order; only the mu partial-sum association changes.

#define B_TOT 2560
#define TB 32
#define NB (B_TOT/TB)
#define TBD 8
#define NBD (B_TOT/TBD)

__device__ __forceinline__ int ROFF(int i){ return (i*(i+1))>>1; }
// padded-row packed lower triangle: row i starts at rowStart(i), 16B aligned
__device__ __forceinline__ int rowStart(int i){
  int a=i>>2, b=i&3;
  return ((a+1)*((a<<1)+b))<<2;
}
#define TRI_SZ 8448

__device__ __forceinline__ int rowOfIdx(int idx){
  int i = (int)((sqrtf(8.f*(float)idx+1.f)-1.f)*0.5f);
  while (((i+1)*(i+2)>>1) <= idx) ++i;
  while (((i*(i+1))>>1) > idx) --i;
  return i;
}

// ---- Gauss-Jordan 16x16 diag block: factor AND invert (lanes 0..15 of one wave)
// On exit diag slots hold Linv (lower). ----
__device__ __forceinline__ void chol_diag_gj(float* tri, int c0, int lane){
  float rowA[16], rowW[16];
  const int r = lane;
  #pragma unroll
  for (int j=0;j<16;++j){ rowA[j]=0.f; rowW[j]=0.f; }
  if (r < 16){
    const float* src = &tri[rowStart(c0+r)+c0];
    #pragma unroll
    for (int q=0;q<4;++q){
      if (q <= (r>>2)){
        float4 w = *(const float4*)&src[4*q];
        rowA[4*q+0]=w.x; rowA[4*q+1]=w.y; rowA[4*q+2]=w.z; rowA[4*q+3]=w.w;
      }
    }
    #pragma unroll
    for (int j=0;j<16;++j) if (j>r) rowA[j]=0.f;
    #pragma unroll
    for (int j=0;j<16;++j) rowW[j] = (j==r)?1.f:0.f;
  }
  #pragma unroll
  for (int k=0;k<16;++k){
    float akk = __shfl(rowA[k], k, 64);
    akk = fmaxf(akk, 1e-12f);
    float linv = rsqrtf(akk);
    float lrk = rowA[k]*linv;
    if (r==k){
      #pragma unroll
      for (int c=0;c<16;++c) rowW[c] *= linv;
    }
    #pragma unroll
    for (int j=k+1;j<16;++j){
      float ljk = __shfl(lrk, j, 64);
      if (r>=j) rowA[j] = fmaf(-lrk, ljk, rowA[j]);
    }
    #pragma unroll
    for (int c=0;c<=k;++c){
      float wkc = __shfl(rowW[c], k, 64);
      if (r>k) rowW[c] = fmaf(-lrk, wkc, rowW[c]);
    }
  }
  if (r < 16){
    float* dst = &tri[rowStart(c0+r)+c0];
    #pragma unroll
    for (int q=0;q<4;++q){
      if (q <= (r>>2)){
        float4 w; w.x=rowW[4*q+0]; w.y=rowW[4*q+1]; w.z=rowW[4*q+2]; w.w=rowW[4*q+3];
        *(float4*)&dst[4*q] = w;
      }
    }
  }
}

// ---- 8x8 trailing tile (k_prepA only) ----
__device__ __forceinline__ void trail_tile8(float* tri, int pc0, int i0, int j0,
                                            bool diag){
  float4 Pi[8][4], Pj[8][4];
  #pragma unroll
  for (int ii=0;ii<8;++ii){
    const float* rp = &tri[rowStart(i0+ii)+pc0];
    #pragma unroll
    for (int q=0;q<4;++q) Pi[ii][q] = *(const float4*)&rp[4*q];
  }
  #pragma unroll
  for (int jj=0;jj<8;++jj){
    const float* rp = &tri[rowStart(j0+jj)+pc0];
    #pragma unroll
    for (int q=0;q<4;++q) Pj[jj][q] = *(const float4*)&rp[4*q];
  }
  float acc[8][8];
  #pragma unroll
  for (int ii=0;ii<8;++ii)
    #pragma unroll
    for (int jj=0;jj<8;++jj) acc[ii][jj]=0.f;
  #pragma unroll
  for (int q=0;q<4;++q){
    #pragma unroll
    for (int ii=0;ii<8;++ii){
      #pragma unroll
      for (int jj=0;jj<8;++jj){
        acc[ii][jj] = fmaf(Pi[ii][q].x, Pj[jj][q].x, acc[ii][jj]);
        acc[ii][jj] = fmaf(Pi[ii][q].y, Pj[jj][q].y, acc[ii][jj]);
        acc[ii][jj] = fmaf(Pi[ii][q].z, Pj[jj][q].z, acc[ii][jj]);
        acc[ii][jj] = fmaf(Pi[ii][q].w, Pj[jj][q].w, acc[ii][jj]);
      }
    }
  }
  if (!diag){
    #pragma unroll
    for (int ii=0;ii<8;++ii){
      float4* p = (float4*)&tri[rowStart(i0+ii)+j0];
      float4 v0=p[0], v1=p[1];
      v0.x-=acc[ii][0]; v0.y-=acc[ii][1]; v0.z-=acc[ii][2]; v0.w-=acc[ii][3];
      v1.x-=acc[ii][4]; v1.y-=acc[ii][5]; v1.z-=acc[ii][6]; v1.w-=acc[ii][7];
      p[0]=v0; p[1]=v1;
    }
  } else {
    #pragma unroll
    for (int ii=0;ii<8;++ii){
      float4* p = (float4*)&tri[rowStart(i0+ii)+j0];
      const int nq = (ii>>2)+1;
      #pragma unroll
      for (int q=0;q<2;++q){
        if (q<nq){
          float4 v=p[q];
          v.x-=acc[ii][4*q+0]; v.y-=acc[ii][4*q+1];
          v.z-=acc[ii][4*q+2]; v.w-=acc[ii][4*q+3];
          p[q]=v;
        }
      }
    }
  }
}

// ---- 4x4 trailing tile (k_C): float4 RMW; diag-tile pad writes are benign ----
__device__ __forceinline__ void trail_tile4(float* tri, int pc0, int i0, int j0){
  float4 Pi[4][4], Pj[4][4];
  #pragma unroll
  for (int ii=0;ii<4;++ii){
    const float* rp = &tri[rowStart(i0+ii)+pc0];
    #pragma unroll
    for (int q=0;q<4;++q) Pi[ii][q] = *(const float4*)&rp[4*q];
  }
  #pragma unroll
  for (int jj=0;jj<4;++jj){
    const float* rp = &tri[rowStart(j0+jj)+pc0];
    #pragma unroll
    for (int q=0;q<4;++q) Pj[jj][q] = *(const float4*)&rp[4*q];
  }
  float acc[4][4];
  #pragma unroll
  for (int ii=0;ii<4;++ii)
    #pragma unroll
    for (int jj=0;jj<4;++jj) acc[ii][jj]=0.f;
  #pragma unroll
  for (int q=0;q<4;++q){
    #pragma unroll
    for (int ii=0;ii<4;++ii){
      #pragma unroll
      for (int jj=0;jj<4;++jj){
        acc[ii][jj] = fmaf(Pi[ii][q].x, Pj[jj][q].x, acc[ii][jj]);
        acc[ii][jj] = fmaf(Pi[ii][q].y, Pj[jj][q].y, acc[ii][jj]);
        acc[ii][jj] = fmaf(Pi[ii][q].z, Pj[jj][q].z, acc[ii][jj]);
        acc[ii][jj] = fmaf(Pi[ii][q].w, Pj[jj][q].w, acc[ii][jj]);
      }
    }
  }
  #pragma unroll
  for (int ii=0;ii<4;++ii){
    float4* p = (float4*)&tri[rowStart(i0+ii)+j0];
    float4 v=p[0];
    v.x-=acc[ii][0]; v.y-=acc[ii][1]; v.z-=acc[ii][2]; v.w-=acc[ii][3];
    p[0]=v;
  }
}

// ---- panel solve row: X = A * Linv^T (one row) ----
__device__ __forceinline__ void panel_row(float* tri, int c0, int r){
  const int rb = rowStart(r)+c0;
  float a[16];
  #pragma unroll
  for (int q=0;q<4;++q){
    float4 w = *(const float4*)&tri[rb+4*q];
    a[4*q+0]=w.x; a[4*q+1]=w.y; a[4*q+2]=w.z; a[4*q+3]=w.w;
  }
  float x[16];
  #pragma unroll
  for (int c=0;c<16;++c){
    float acc=0.f;
    const int lb = rowStart(c0+c)+c0;
    #pragma unroll
    for (int q=0;q<=(c>>2);++q){
      float4 w = *(const float4*)&tri[lb+4*q];
      if (4*q+0<=c) acc = fmaf(w.x, a[4*q+0], acc);
      if (4*q+1<=c) acc = fmaf(w.y, a[4*q+1], acc);
      if (4*q+2<=c) acc = fmaf(w.z, a[4*q+2], acc);
      if (4*q+3<=c) acc = fmaf(w.w, a[4*q+3], acc);
    }
    x[c]=acc;
  }
  #pragma unroll
  for (int q=0;q<4;++q){
    float4 w; w.x=x[4*q+0]; w.y=x[4*q+1]; w.z=x[4*q+2]; w.w=x[4*q+3];
    *(float4*)&tri[rb+4*q] = w;
  }
}

// ---- 256-thread blocked Cholesky (k_prepA only) ----
__device__ void chol_factor(float* tri, int t, int lane, int wid){
  for (int kb=0; kb<8; ++kb){
    const int c0 = kb*16;
    if (wid==(kb&3)) chol_diag_gj(tri, c0, lane);
    __syncthreads();
    const int rem = 112 - c0;
    if (t < rem) panel_row(tri, c0, c0+16+t);
    __syncthreads();
    if (rem > 0){
      const int base = c0+16;
      const int T = rem>>3;
      const int ntile = (T*(T+1))>>1;
      for (int idx=t; idx<ntile; idx+=256){
        int I = rowOfIdx(idx);
        int J = idx - ROFF(I);
        trail_tile8(tri, c0, base+8*I, base+8*J, I==J);
      }
    }
    __syncthreads();
  }
}

// ---- 128-thread blocked Cholesky (k_C, round-11 structure) ----
__device__ void chol_factor_w2(float* tri, int t, int lane, int wid){
  for (int kb=0; kb<8; ++kb){
    const int c0 = kb*16;
    if (wid==0) chol_diag_gj(tri, c0, lane);
    __syncthreads();
    const int rem = 112 - c0;
    if (t < rem) panel_row(tri, c0, c0+16+t);
    __syncthreads();
    if (rem > 0){
      const int base = c0+16;
      const int R = rem>>2;
      const int ntile = (R*(R+1))>>1;
      for (int idx=t; idx<ntile; idx+=128){
        int I = rowOfIdx(idx);
        int J = idx - ROFF(I);
        trail_tile4(tri, c0, base+4*I, base+4*J);
      }
    }
    __syncthreads();
  }
}

// 128-thread forward/backward solve; diag slots hold Linv; rhs in LDS
__device__ void tri_solve_w2(const float* tri, float* rhs, int t){
  for (int kb=0;kb<8;++kb){
    const int c0=kb*16;
    if (t<16){
      const int c=t;
      const float* lrow = &tri[rowStart(c0+c)+c0];
      float acc=0.f;
      #pragma unroll
      for (int cp=0;cp<16;++cp) if (cp<=c) acc = fmaf(lrow[cp], rhs[c0+cp], acc);
      rhs[c0+c] = acc;
    }
    __syncthreads();
    const int rem = 112-c0;
    if (t<rem){
      const int r = c0+16+t;
      const int rb = rowStart(r)+c0;
      float acc = rhs[r];
      #pragma unroll
      for (int q=0;q<4;++q){
        float4 w = *(const float4*)&tri[rb+4*q];
        acc = fmaf(-w.x, rhs[c0+4*q+0], acc);
        acc = fmaf(-w.y, rhs[c0+4*q+1], acc);
        acc = fmaf(-w.z, rhs[c0+4*q+2], acc);
        acc = fmaf(-w.w, rhs[c0+4*q+3], acc);
      }
      rhs[r] = acc;
    }
    __syncthreads();
  }
  for (int kb=7;kb>=0;--kb){
    const int c0=kb*16;
    if (t<16){
      const int c=t;
      float acc=0.f;
      #pragma unroll
      for (int cp=0;cp<16;++cp)
        if (cp>=c) acc = fmaf(tri[rowStart(c0+cp)+c0+c], rhs[c0+cp], acc);
      rhs[c0+c] = acc;
    }
    __syncthreads();
    if (t<c0){
      float acc = rhs[t];
      #pragma unroll
      for (int c=0;c<16;++c) acc = fmaf(-tri[rowStart(c0+c)+t], rhs[c0+c], acc);
      rhs[t]=acc;
    }
    __syncthreads();
  }
}

// ---- k_prepA: factor chol(Q), dump triangle to global ----
__global__ __launch_bounds__(256) void k_prepA(const float* __restrict__ Q,
                                               float* __restrict__ TRIQ){
  __shared__ __align__(16) float tri[TRI_SZ];
  const int t = threadIdx.x;
  const int lane = t&63, wid = t>>6;
  for (int idx=t; idx<8256; idx+=256){
    int i = rowOfIdx(idx); int j = idx - ROFF(i);
    tri[rowStart(i)+j] = Q[i*128+j];
  }
  __syncthreads();
  chol_factor(tri, t, lane, wid);
  for (int idx=t; idx<TRI_SZ; idx+=256) TRIQ[idx]=tri[idx];
}

// ---- k_prepB: 8 blocks, each one 32-col solve chunk -> Qi or M1 ----
__global__ __launch_bounds__(256) void k_prepB(const float* __restrict__ TRIQ,
        const float* __restrict__ Gm, float* __restrict__ Qi, float* __restrict__ M1)
{
  __shared__ __align__(16) float tri[TRI_SZ];
  __shared__ float Xl[128*32];
  const int t = threadIdx.x, cc = blockIdx.x;
  const int a0 = (cc&3)*32;
  const bool ident = (cc<4);
  for (int idx=t; idx<TRI_SZ; idx+=256) tri[idx]=TRIQ[idx];
  for (int idx=t; idx<4096; idx+=256){
    int i=idx>>5, j=idx&31;
    Xl[idx] = ident ? ((i==(a0+j))?1.f:0.f) : Gm[(a0+j)*128+i];
  }
  __syncthreads();
  for (int kb=0;kb<8;++kb){                    // forward: X := L^{-1} X
    const int c0=kb*16;
    if (t<32){
      float v[16], x[16];
      #pragma unroll
      for (int c=0;c<16;++c) v[c]=Xl[(c0+c)*32+t];
      #pragma unroll
      for (int c=0;c<16;++c){
        float acc=0.f;
        const int lb=rowStart(c0+c)+c0;
        #pragma unroll
        for (int cp=0;cp<16;++cp) if (cp<=c) acc=fmaf(tri[lb+cp], v[cp], acc);
        x[c]=acc;
      }
      #pragma unroll
      for (int c=0;c<16;++c) Xl[(c0+c)*32+t]=x[c];
    }
    __syncthreads();
    const int rem=112-c0;
    for (int rr=(t>>5); rr<rem; rr+=8){
      const int r=c0+16+rr, j=t&31;
      float acc=Xl[r*32+j];
      #pragma unroll
      for (int c=0;c<16;++c) acc = fmaf(-tri[rowStart(r)+c0+c], Xl[(c0+c)*32+j], acc);
      Xl[r*32+j]=acc;
    }
    __syncthreads();
  }
  for (int kb=7;kb>=0;--kb){                   // backward: X := L^{-T} X
    const int c0=kb*16;
    if (t<32){
      float v[16], x[16];
      #pragma unroll
      for (int c=0;c<16;++c) v[c]=Xl[(c0+c)*32+t];
      #pragma unroll
      for (int c=0;c<16;++c){
        float acc=0.f;
        #pragma unroll
        for (int cp=0;cp<16;++cp) if (cp>=c) acc=fmaf(tri[rowStart(c0+cp)+c0+c], v[cp], acc);
        x[c]=acc;
      }
      #pragma unroll
      for (int c=0;c<16;++c) Xl[(c0+c)*32+t]=x[c];
    }
    __syncthreads();
    for (int rr=(t>>5); rr<c0; rr+=8){
      const int j=t&31;
      float acc=Xl[rr*32+j];
      #pragma unroll
      for (int c=0;c<16;++c) acc = fmaf(-tri[rowStart(c0+c)+rr], Xl[(c0+c)*32+j], acc);
      Xl[rr*32+j]=acc;
    }
    __syncthreads();
  }
  float* dst = ident ? Qi : M1;
  for (int idx=t; idx<4096; idx+=256){
    int i=idx>>5, j=idx&31;
    dst[i*128+a0+j] = Xl[idx];
  }
}

__global__ __launch_bounds__(256) void k_kmat(const float* __restrict__ Gm,
        const float* __restrict__ M1, float* __restrict__ K, float* __restrict__ Kd){
  const int idx = blockIdx.x*256 + threadIdx.x;
  const int a = idx>>7, bcol = idx&127;
  float a0=0.f,a1=0.f,a2=0.f,a3=0.f;
  #pragma unroll
  for (int j=0;j<128;j+=4){
    a0 = fmaf(Gm[a*128+j+0], M1[(j+0)*128+bcol], a0);
    a1 = fmaf(Gm[a*128+j+1], M1[(j+1)*128+bcol], a1);
    a2 = fmaf(Gm[a*128+j+2], M1[(j+2)*128+bcol], a2);
    a3 = fmaf(Gm[a*128+j+3], M1[(j+3)*128+bcol], a3);
  }
  float acc = (a0+a1)+(a2+a3);
  K[idx] = acc;
  if (a==bcol) Kd[a]=acc;
}

__global__ __launch_bounds__(256) void k_init(const float* __restrict__ p,
    float* __restrict__ Pt, float* __restrict__ S, float* __restrict__ LAM,
    float* __restrict__ GZ, float* __restrict__ QZ, float* __restrict__ Zst){
  int idx = blockIdx.x*256 + threadIdx.x;
  if (idx < 128*B_TOT){
    int i = idx/B_TOT, b = idx - i*B_TOT;
    Pt[idx] = p[b*128+i];
    S[idx]=1.f; LAM[idx]=1.f; GZ[idx]=0.f; QZ[idx]=0.f; Zst[idx]=0.f;
  }
}

// ---- k_B: prologue only: stage1 + rhs + tv (runs once) ----
__global__ __launch_bounds__(256) void k_B(const float* __restrict__ G,
    const float* __restrict__ M1, const float* __restrict__ Pt,
    const float* __restrict__ h,
    const float* __restrict__ S, const float* __restrict__ LAM,
    const float* __restrict__ GZ, const float* __restrict__ QZ,
    float* __restrict__ RHS, float* __restrict__ TV){
  __shared__ float wm_l[128*33];
  __shared__ float rhs_l[128*33];
  __shared__ float part_l[8*33];
  __shared__ float mu_l[TB];
  __shared__ float h_l[128];
  const int t=threadIdx.x, g=t>>5, bl=t&31;
  const int b = blockIdx.x*TB + bl;
  if (t<128) h_l[t]=h[t];
  __syncthreads();
  float sv[16], lv[16], rpv[16];
  float prod=0.f;
  #pragma unroll
  for (int q=0;q<16;++q){
    int i = g + 8*q;
    float s = S[i*B_TOT+b], l = LAM[i*B_TOT+b], gz = GZ[i*B_TOT+b];
    sv[q]=s; lv[q]=l; rpv[q]=gz+s-h_l[i];
    prod += s*l;
  }
  part_l[g*33+bl] = prod;
  __syncthreads();
  if (g==0){
    float m=0.f;
    #pragma unroll
    for (int q=0;q<8;++q) m += part_l[q*33+bl];
    mu_l[bl] = m*(1.f/128.f);
  }
  __syncthreads();
  const float mu = mu_l[bl];
  #pragma unroll
  for (int q=0;q<16;++q){
    int i=g+8*q;
    float rc = sv[q]*lv[q] - 0.1f*mu;
    wm_l[i*33+bl] = (rc - lv[q]*rpv[q])/sv[q] - lv[q];
  }
  __syncthreads();
  const int r0 = g*16;
  float acc[16];
  #pragma unroll
  for (int q=0;q<16;++q) acc[q] = -(QZ[(r0+q)*B_TOT+b] + Pt[(r0+q)*B_TOT+b]);
  #pragma unroll 2
  for (int j=0;j<128;++j){
    float wmv = wm_l[j*33+bl];
    const float4* gp = (const float4*)&G[j*128+r0];
    #pragma unroll
    for (int q4=0;q4<4;++q4){
      float4 gv = gp[q4];
      acc[4*q4+0]=fmaf(gv.x,wmv,acc[4*q4+0]);
      acc[4*q4+1]=fmaf(gv.y,wmv,acc[4*q4+1]);
      acc[4*q4+2]=fmaf(gv.z,wmv,acc[4*q4+2]);
      acc[4*q4+3]=fmaf(gv.w,wmv,acc[4*q4+3]);
    }
  }
  #pragma unroll
  for (int q=0;q<16;++q){
    rhs_l[(r0+q)*33+bl]=acc[q];
    RHS[(r0+q)*B_TOT+b]=acc[q];
  }
  __syncthreads();
  #pragma unroll
  for (int q=0;q<16;++q) acc[q]=0.f;
  #pragma unroll 2
  for (int j=0;j<128;++j){
    float rv = rhs_l[j*33+bl];
    const float4* mp = (const float4*)&M1[j*128+r0];
    #pragma unroll
    for (int q4=0;q4<4;++q4){
      float4 mv = mp[q4];
      acc[4*q4+0]=fmaf(mv.x,rv,acc[4*q4+0]);
      acc[4*q4+1]=fmaf(mv.y,rv,acc[4*q4+1]);
      acc[4*q4+2]=fmaf(mv.z,rv,acc[4*q4+2]);
      acc[4*q4+3]=fmaf(mv.w,rv,acc[4*q4+3]);
    }
  }
  #pragma unroll
  for (int q=0;q<16;++q) TV[(r0+q)*B_TOT+b]=acc[q];
}

// ---- k_C: 128 threads per batch (round-11 structure, verbatim) ----
__global__ __launch_bounds__(128) void k_C(const float* __restrict__ K,
    const float* __restrict__ Kd, const float* __restrict__ h,
    const float* __restrict__ TV,
    float* __restrict__ S, float* __restrict__ LAM, float* __restrict__ GZ,
    float* __restrict__ Y, float* __restrict__ ALPHA){
  __shared__ __align__(16) float tri[TRI_SZ];
  __shared__ float scl_l[128];
  __shared__ float sh_t[128];
  __shared__ float red[2];
  const int t = threadIdx.x, b = blockIdx.x;
  const int lane = t&63, wid = t>>6;
  float s_t=S[t*B_TOT+b], l_t=LAM[t*B_TOT+b], g_t=GZ[t*B_TOT+b];
  float rp_t = g_t + s_t - h[t];
  float prod = s_t*l_t;
  #pragma unroll
  for (int o=32;o>0;o>>=1) prod += __shfl_xor(prod,o,64);
  if (lane==0) red[wid]=prod;
  __syncthreads();
  const float mu = (red[0]+red[1])*(1.f/128.f);
  float rc_t = s_t*l_t - 0.1f*mu;
  float di_t = fminf(s_t/l_t, 1e30f);
  float sc_t = rsqrtf(Kd[t]+di_t);
  scl_l[t]=sc_t;
  sh_t[t]=TV[t*B_TOT+b]*sc_t;
  __syncthreads();
  // build equilibrated triangle (unit diag): row sweep, coalesced K reads
  #pragma unroll 4
  for (int i=0;i<128;++i){
    if (t<=i) tri[rowStart(i)+t] = (t==i)?1.f : K[i*128+t]*scl_l[i]*sc_t;
  }
  __syncthreads();
  chol_factor_w2(tri, t, lane, wid);
  tri_solve_w2(tri, sh_t, t);
  float y = sh_t[t]*sc_t;
  float gd = di_t*y;                     // G dz = Dinv .* y (Woodbury identity)
  float ds = -rp_t - gd;
  float dl = (-rc_t - l_t*ds)/s_t;
  float ra = 1e9f;
  if (ds<0.f) ra = -s_t/ds;
  if (dl<0.f) ra = fminf(ra,-l_t/dl);
  #pragma unroll
  for (int o=32;o>0;o>>=1) ra = fminf(ra,__shfl_xor(ra,o,64));
  __syncthreads();
  if (lane==0) red[wid]=ra;
  __syncthreads();
  const float alpha = fminf(1.0f, 0.99f*fminf(red[0],red[1]));
  S[t*B_TOT+b]   = s_t + alpha*ds;
  LAM[t*B_TOT+b] = l_t + alpha*dl;
  GZ[t*B_TOT+b]  = g_t + alpha*gd;
  Y[t*B_TOT+b]   = y;
  if (t==0) ALPHA[b]=alpha;
}

// ---- k_DB: fused k_D(iter i) + k_B(iter i+1); TBD=8 batches/block ----
// mapping: bl = t&7 (batch lane), g = t>>3 (row group), rows r0 = g*4 .. +3
__global__ __launch_bounds__(256) void k_DB(const float* __restrict__ G,
    const float* __restrict__ Qi, const float* __restrict__ M1,
    const float* __restrict__ Pt, const float* __restrict__ h,
    const float* __restrict__ S, const float* __restrict__ LAM,
    const float* __restrict__ GZ,
    const float* __restrict__ Y, const float* __restrict__ ALPHA,
    float* __restrict__ Zst, float* __restrict__ QZ,
    float* __restrict__ RHS, float* __restrict__ TV){
  __shared__ float bufA[128*9];    // y -> qz_new -> rhs_new
  __shared__ float bufB[128*9];    // v -> wm
  __shared__ float part_l[32*9];
  __shared__ float mu_l[TBD];
  __shared__ float h_l[128];
  const int t=threadIdx.x, g=t>>3, bl=t&7;
  const int b = blockIdx.x*TBD + bl;
  const int r0 = g*4;
  if (t<128) h_l[t]=h[t];
  #pragma unroll
  for (int q=0;q<4;++q) bufA[(r0+q)*9+bl] = Y[(r0+q)*B_TOT+b];
  const float alpha = ALPHA[b];
  __syncthreads();
  // ---- part 1: v = RHS - G^T y ----
  float acc[4];
  #pragma unroll
  for (int q=0;q<4;++q) acc[q]=RHS[(r0+q)*B_TOT+b];
  #pragma unroll 4
  for (int j=0;j<128;++j){
    float yv = bufA[j*9+bl];
    float4 gv = *(const float4*)&G[j*128+r0];
    acc[0]=fmaf(-gv.x,yv,acc[0]);
    acc[1]=fmaf(-gv.y,yv,acc[1]);
    acc[2]=fmaf(-gv.z,yv,acc[2]);
    acc[3]=fmaf(-gv.w,yv,acc[3]);
  }
  __syncthreads();   // all reads of bufA(y) done
  #pragma unroll
  for (int q=0;q<4;++q){
    const int i=r0+q;
    float qz_new = QZ[i*B_TOT+b] + alpha*acc[q];   // qz += a*v (Q dz == v)
    QZ[i*B_TOT+b] = qz_new;
    bufB[i*9+bl] = acc[q];                         // v
    bufA[i*9+bl] = qz_new;
  }
  __syncthreads();
  // ---- dz = Qi v ; z += a dz ----
  #pragma unroll
  for (int q=0;q<4;++q) acc[q]=0.f;
  #pragma unroll 4
  for (int j=0;j<128;++j){
    float vv = bufB[j*9+bl];
    float4 qv = *(const float4*)&Qi[j*128+r0];
    acc[0]=fmaf(qv.x,vv,acc[0]);
    acc[1]=fmaf(qv.y,vv,acc[1]);
    acc[2]=fmaf(qv.z,vv,acc[2]);
    acc[3]=fmaf(qv.w,vv,acc[3]);
  }
  #pragma unroll
  for (int q=0;q<4;++q){
    float* zp=&Zst[(r0+q)*B_TOT+b];
    *zp = *zp + alpha*acc[q];
  }
  __syncthreads();   // all reads of bufB(v) done
  // ---- part 2: k_B stage1 (post-k_C state) ----
  float sv[4], lv[4], rpv[4];
  float prod=0.f;
  #pragma unroll
  for (int q=0;q<4;++q){
    const int i=r0+q;
    float s = S[i*B_TOT+b], l = LAM[i*B_TOT+b], gz = GZ[i*B_TOT+b];
    sv[q]=s; lv[q]=l; rpv[q]=gz+s-h_l[i];
    prod += s*l;
  }
  part_l[g*9+bl] = prod;
  __syncthreads();
  if (t<TBD){
    float m=0.f;
    #pragma unroll
    for (int r=0;r<32;++r) m += part_l[r*9+t];
    mu_l[t] = m*(1.f/128.f);
  }
  __syncthreads();
  const float mu = mu_l[bl];
  #pragma unroll
  for (int q=0;q<4;++q){
    const int i=r0+q;
    float rc = sv[q]*lv[q] - 0.1f*mu;
    bufB[i*9+bl] = (rc - lv[q]*rpv[q])/sv[q] - lv[q];   // wm
  }
  __syncthreads();
  // ---- rhs = -(qz_new + p) + G^T wm ----
  #pragma unroll
  for (int q=0;q<4;++q) acc[q] = -(bufA[(r0+q)*9+bl] + Pt[(r0+q)*B_TOT+b]);
  #pragma unroll 4
  for (int j=0;j<128;++j){
    float wmv = bufB[j*9+bl];
    float4 gv = *(const float4*)&G[j*128+r0];
    acc[0]=fmaf(gv.x,wmv,acc[0]);
    acc[1]=fmaf(gv.y,wmv,acc[1]);
    acc[2]=fmaf(gv.z,wmv,acc[2]);
    acc[3]=fmaf(gv.w,wmv,acc[3]);
  }
  __syncthreads();   // wm reads done; bufA overwrite safe
  #pragma unroll
  for (int q=0;q<4;++q){
    RHS[(r0+q)*B_TOT+b]=acc[q];
    bufA[(r0+q)*9+bl]=acc[q];
  }
  __syncthreads();
  // ---- tv = G Qi rhs (via M1^T) ----
  #pragma unroll
  for (int q=0;q<4;++q) acc[q]=0.f;
  #pragma unroll 4
  for (int j=0;j<128;++j){
    float rv = bufA[j*9+bl];
    float4 mv = *(const float4*)&M1[j*128+r0];
    acc[0]=fmaf(mv.x,rv,acc[0]);
    acc[1]=fmaf(mv.y,rv,acc[1]);
    acc[2]=fmaf(mv.z,rv,acc[2]);
    acc[3]=fmaf(mv.w,rv,acc[3]);
  }
  #pragma unroll
  for (int q=0;q<4;++q) TV[(r0+q)*B_TOT+b]=acc[q];
}

// ---- k_D: final iteration tail (v, dz, z, qz); TBD=8 mapping ----
__global__ __launch_bounds__(256) void k_D(const float* __restrict__ G,
    const float* __restrict__ Qi, const float* __restrict__ RHS,
    const float* __restrict__ Y, const float* __restrict__ ALPHA,
    float* __restrict__ Zst, float* __restrict__ QZ){
  __shared__ float y_l[128*9];
  __shared__ float v_l[128*9];
  const int t=threadIdx.x, g=t>>3, bl=t&7;
  const int b = blockIdx.x*TBD + bl;
  const int r0 = g*4;
  #pragma unroll
  for (int q=0;q<4;++q) y_l[(r0+q)*9+bl] = Y[(r0+q)*B_TOT+b];
  const float alpha = ALPHA[b];
  __syncthreads();
  float acc[4];
  #pragma unroll
  for (int q=0;q<4;++q) acc[q]=RHS[(r0+q)*B_TOT+b];
  #pragma unroll 4
  for (int j=0;j<128;++j){
    float yv = y_l[j*9+bl];
    float4 gv = *(const float4*)&G[j*128+r0];
    acc[0]=fmaf(-gv.x,yv,acc[0]);
    acc[1]=fmaf(-gv.y,yv,acc[1]);
    acc[2]=fmaf(-gv.z,yv,acc[2]);
    acc[3]=fmaf(-gv.w,yv,acc[3]);
  }
  #pragma unroll
  for (int q=0;q<4;++q){
    const int i=r0+q;
    v_l[i*9+bl]=acc[q];
    float* qp=&QZ[i*B_TOT+b];
    *qp = *qp + alpha*acc[q];
  }
  __syncthreads();
  #pragma unroll
  for (int q=0;q<4;++q) acc[q]=0.f;
  #pragma unroll 4
  for (int j=0;j<128;++j){
    float vv = v_l[j*9+bl];
    float4 qv = *(const float4*)&Qi[j*128+r0];
    acc[0]=fmaf(qv.x,vv,acc[0]);
    acc[1]=fmaf(qv.y,vv,acc[1]);
    acc[2]=fmaf(qv.z,vv,acc[2]);
    acc[3]=fmaf(qv.w,vv,acc[3]);
  }
  #pragma unroll
  for (int q=0;q<4;++q){
    float* zp=&Zst[(r0+q)*B_TOT+b];
    *zp = *zp + alpha*acc[q];
  }
}

// out = log_softmax(Z.reshape(10, 32768), axis=1), Z stored n-major [i][B]
__global__ __launch_bounds__(1024) void k_logsoftmax(const float* __restrict__ Zst,
                                                     float* __restrict__ out){
  __shared__ float red[16];
  __shared__ float sval[2];
  const int r = blockIdx.x, t = threadIdx.x;
  float m = -1e30f;
  for (int k=t;k<32768;k+=1024){
    float v = Zst[(k&127)*B_TOT + r*256 + (k>>7)];
    m = fmaxf(m, v);
  }
  #pragma unroll
  for (int o=32;o>0;o>>=1) m = fmaxf(m, __shfl_down(m,o,64));
  if ((t&63)==0) red[t>>6] = m;
  __syncthreads();
  if (t==0){ float mm=red[0]; for (int w=1;w<16;++w) mm=fmaxf(mm,red[w]); sval[0]=mm; }
  __syncthreads();
  const float mx = sval[0];
  float s=0.f;
  for (int k=t;k<32768;k+=1024){
    float v = Zst[(k&127)*B_TOT + r*256 + (k>>7)];
    s += expf(v-mx);
  }
  #pragma unroll
  for (int o=32;o>0;o>>=1) s += __shfl_down(s,o,64);
  if ((t&63)==0) red[t>>6]=s;
  __syncthreads();
  if (t==0){ float ss=0.f; for (int w=0;w<16;++w) ss+=red[w]; sval[1]=logf(ss); }
  __syncthreads();
  const float lse = sval[1];
  for (int k=t;k<32768;k+=1024){
    float v = Zst[(k&127)*B_TOT + r*256 + (k>>7)];
    out[(size_t)r*32768+k] = v-mx-lse;
  }
}

extern "C" void kernel_launch(void* const* d_in, const int* in_sizes, int n_in,
                              void* d_out, int out_size, void* d_ws, size_t ws_size,
                              hipStream_t stream){
  // inputs: 0=x (unused), 1=Q[128x128], 2=p[2560x128], 3=G[128x128], 4=h[128], 5=m
  const float* Q = (const float*)d_in[1];
  const float* p = (const float*)d_in[2];
  const float* G = (const float*)d_in[3];
  const float* h = (const float*)d_in[4];
  float* ws  = (float*)d_ws;
  const int NE = 128*B_TOT;
  float* Zst = ws;                       // NE
  float* Qi  = Zst + NE;                 // 16384
  float* M1  = Qi + 16384;
  float* K   = M1 + 16384;
  float* Kd  = K + 16384;                // 128
  float* ALPHA = Kd + 128;               // 2560
  float* Pt  = ALPHA + 2560;             // NE
  float* S   = Pt + NE;
  float* LAM = S + NE;
  float* GZ  = LAM + NE;
  float* QZ  = GZ + NE;
  float* RHS = QZ + NE;
  float* TV  = RHS + NE;
  float* Y   = TV + NE;
  float* TRIQ= Y + NE;                   // 8448
  float* out = (float*)d_out;

  hipLaunchKernelGGL(k_prepA, dim3(1), dim3(256), 0, stream, Q, TRIQ);
  hipLaunchKernelGGL(k_prepB, dim3(8), dim3(256), 0, stream, TRIQ, G, Qi, M1);
  hipLaunchKernelGGL(k_kmat, dim3(64), dim3(256), 0, stream, G, M1, K, Kd);
  hipLaunchKernelGGL(k_init, dim3((NE+255)/256), dim3(256), 0, stream,
                     p, Pt, S, LAM, GZ, QZ, Zst);
  hipLaunchKernelGGL(k_B, dim3(NB), dim3(256), 0, stream,
                     G, M1, Pt, h, S, LAM, GZ, QZ, RHS, TV);
  for (int it=0; it<20; ++it){
    hipLaunchKernelGGL(k_C, dim3(B_TOT), dim3(128), 0, stream,
                       K, Kd, h, TV, S, LAM, GZ, Y, ALPHA);
    if (it < 19){
      hipLaunchKernelGGL(k_DB, dim3(NBD), dim3(256), 0, stream,
                         G, Qi, M1, Pt, h, S, LAM, GZ, Y, ALPHA,
                         Zst, QZ, RHS, TV);
    } else {
      hipLaunchKernelGGL(k_D, dim3(NBD), dim3(256), 0, stream,
                         G, Qi, RHS, Y, ALPHA, Zst, QZ);
    }
  }
  hipLaunchKernelGGL(k_logsoftmax, dim3(10), dim3(1024), 0, stream, Zst, out);
}